// Round 8
// baseline (465.124 us; speedup 1.0000x reference)
//
#include <hip/hip_runtime.h>

#define BB 4
#define SS 2048
#define DD 1024
#define HH 16
#define PFF 4096
#define MR 8192

typedef unsigned short u16;
typedef __attribute__((ext_vector_type(8))) short s16x8;   // MFMA A/B frag (8 bf16)
typedef __attribute__((ext_vector_type(4))) float f32x4v;  // 16x16 C/D frag
typedef __attribute__((ext_vector_type(16))) float f32x16; // 32x32 C/D frag
typedef __attribute__((ext_vector_type(4))) unsigned short u16x4;
typedef __attribute__((ext_vector_type(8))) unsigned short u16x8;

__device__ inline u16 f2bf(float f) {
  union { float f; unsigned u; } v; v.f = f;
  unsigned r = v.u + 0x7FFFu + ((v.u >> 16) & 1u);
  return (u16)(r >> 16);
}

__device__ inline unsigned cvtpk_bf16(float lo, float hi) {
  unsigned r;
  asm("v_cvt_pk_bf16_f32 %0, %1, %2" : "=v"(r) : "v"(lo), "v"(hi));
  return r;
}

__device__ inline void gload16(const void* g, void* l) {
  __builtin_amdgcn_global_load_lds(
      (const __attribute__((address_space(1))) void*)g,
      (__attribute__((address_space(3))) void*)l, 16, 0, 0);
}

__device__ inline f32x4v MFMA(s16x8 a, s16x8 b, f32x4v c) {
  return __builtin_amdgcn_mfma_f32_16x16x32_bf16(a, b, c, 0, 0, 0);
}
__device__ inline f32x16 MFMA32(s16x8 a, s16x8 b, f32x16 c) {
  return __builtin_amdgcn_mfma_f32_32x32x16_bf16(a, b, c, 0, 0, 0);
}

#define RAWBAR()                          \
  do {                                    \
    asm volatile("" ::: "memory");        \
    __builtin_amdgcn_s_barrier();         \
    asm volatile("" ::: "memory");        \
  } while (0)
#define WAITVM(N) asm volatile("s_waitcnt vmcnt(" #N ")" ::: "memory")

// read a b128 fragment from a 64-col bf16 LDS tile with (row&7)<<4 byte-XOR swizzle
__device__ inline s16x8 ldfrag(const u16* base, int row, int colByte) {
  return *(const s16x8*)((const char*)base + row * 128 + (colByte ^ ((row & 7) << 4)));
}

// ---------------------------------------------------------------------------
// 256xBN deep-pipelined bf16 GEMM (T3+T4+T5): C = A[M,K] @ Bt[N,K]^T + bias.
// ---------------------------------------------------------------------------
template <int BN, int RELU, int OUTBF, int SCQ>
__global__ __launch_bounds__(512, 1) void gemm256(
    const u16* __restrict__ A, const u16* __restrict__ Bt,
    const float* __restrict__ bias, float* __restrict__ Cf,
    u16* __restrict__ Cb, int M, int N, int K, int ntx) {
  constexpr int WM = (BN == 256) ? 8 : 4;   // m-frags per wave
  constexpr int HM = WM / 2;                // per phase
  constexpr int BUF = 8192 + BN * 32;       // u16 per ring buffer
  __shared__ __align__(128) u16 lds[3 * BUF];
  const int t = threadIdx.x;
  const int lane = t & 63, w = t >> 6;
  const int wr = (BN == 256) ? (w >> 2) : (w >> 1);
  const int wc = (BN == 256) ? (w & 3) : (w & 1);
  const int g = lane >> 4, q = lane & 15;

  const int cpx = gridDim.x >> 3;
  const int wg = (blockIdx.x & 7) * cpx + (blockIdx.x >> 3);
  const int row0 = (wg / ntx) * 256, col0 = (wg % ntx) * BN;

  f32x4v acc[WM][4];
#pragma unroll
  for (int m = 0; m < WM; ++m)
#pragma unroll
    for (int n = 0; n < 4; ++n) acc[m][n] = (f32x4v){0.f, 0.f, 0.f, 0.f};

  const int sr0 = t >> 2, sc0 = (t & 3) * 8;
  const u16* Ag0 = A + (size_t)(row0 + sr0) * K + sc0;
  const u16* Ag1 = A + (size_t)(row0 + sr0 + 128) * K + sc0;
  const u16* Bg0 = Bt + (size_t)(col0 + sr0) * K + sc0;
  const u16* Bg1 = Bt + (size_t)(col0 + sr0 + 128) * K + sc0;  // BN==256 only
  const int wud = (t & ~63) * 8;

#define STAGE_A(kt, buf)                                          \
  do {                                                            \
    u16* ab_ = &lds[(buf) * BUF];                                 \
    gload16(Ag0 + (kt) * 32, ab_ + wud);                          \
    gload16(Ag1 + (kt) * 32, ab_ + 4096 + wud);                   \
  } while (0)
#define STAGE_B(kt, buf)                                          \
  do {                                                            \
    u16* bb_ = &lds[(buf) * BUF + 8192];                          \
    gload16(Bg0 + (kt) * 32, bb_ + wud);                          \
    if (BN == 256) gload16(Bg1 + (kt) * 32, bb_ + 4096 + wud);    \
  } while (0)

  const int NT = K / 32;
  STAGE_A(0, 0); STAGE_B(0, 0);
  STAGE_A(1, 1); STAGE_B(1, 1);
  if constexpr (BN == 256) WAITVM(4); else WAITVM(3);
  RAWBAR();

  int cur = 0, nxt = 2;
  for (int kt = 0; kt < NT; ++kt) {
    const u16* ab = &lds[cur * BUF];
    const u16* bb = ab + 8192;
    const bool pf = (kt + 2 < NT);
    if (pf) STAGE_A(kt + 2, nxt);
    s16x8 bf_[4], af_[HM];
#pragma unroll
    for (int n = 0; n < 4; ++n)
      bf_[n] = *(const s16x8*)&bb[(wc * 64 + n * 16 + q) * 32 + g * 8];
#pragma unroll
    for (int m = 0; m < HM; ++m)
      af_[m] = *(const s16x8*)&ab[(wr * (WM * 16) + m * 16 + q) * 32 + g * 8];
    RAWBAR();
    __builtin_amdgcn_s_setprio(1);
#pragma unroll
    for (int m = 0; m < HM; ++m)
#pragma unroll
      for (int n = 0; n < 4; ++n) acc[m][n] = MFMA(af_[m], bf_[n], acc[m][n]);
    __builtin_amdgcn_s_setprio(0);
    RAWBAR();
    if (pf) STAGE_B(kt + 2, nxt);
#pragma unroll
    for (int m = 0; m < HM; ++m)
      af_[m] = *(const s16x8*)&ab[(wr * (WM * 16) + (m + HM) * 16 + q) * 32 + g * 8];
    RAWBAR();
    __builtin_amdgcn_s_setprio(1);
#pragma unroll
    for (int m = 0; m < HM; ++m)
#pragma unroll
      for (int n = 0; n < 4; ++n)
        acc[m + HM][n] = MFMA(af_[m], bf_[n], acc[m + HM][n]);
    __builtin_amdgcn_s_setprio(0);
    if (kt + 1 < NT) {
      if (pf) {
        if constexpr (BN == 256) WAITVM(4); else WAITVM(3);
      } else {
        WAITVM(0);
      }
    }
    RAWBAR();
    cur = (cur == 2) ? 0 : cur + 1;
    nxt = (nxt == 2) ? 0 : nxt + 1;
  }
#undef STAGE_A
#undef STAGE_B

#pragma unroll
  for (int n = 0; n < 4; ++n) {
    const int col = col0 + wc * 64 + 16 * n + q;
    const float bv = bias[col];
#pragma unroll
    for (int m = 0; m < WM; ++m) {
#pragma unroll
      for (int r = 0; r < 4; ++r) {
        const int row = row0 + wr * (WM * 16) + 16 * m + 4 * g + r;
        float v = acc[m][n][r] + bv;
        if (RELU) v = fmaxf(v, 0.f);
        if (SCQ && col < DD) v *= 0.18033688011112042f;  // 0.125*log2(e)
        if (OUTBF) Cb[(size_t)row * N + col] = f2bf(v);
        else Cf[(size_t)row * N + col] = v;
      }
    }
  }
}

// ---------------------------------------------------------------------------
// Flash attention v6: k-split waves. 4 waves = 2 q-groups x 2 k-groups;
// each wave: 32 q-rows x its 32 keys of the 64-key tile (halves LDS reads,
// exp2, and pack work per unit of output). No max tracking (Q pre-scaled,
// P = exp2(s) directly) -> partial (O, l) over disjoint key sets simply ADD;
// kg pairs combine through LDS once at the end. l rides the matrix pipe.
// ---------------------------------------------------------------------------
__global__ __launch_bounds__(256, 4) void attn_mfma(
    const u16* __restrict__ qkv, const u16* __restrict__ vt,
    u16* __restrict__ xb) {
  __shared__ __align__(128) u16 lds[16384];  // 32KB

  const int t = threadIdx.x;
  const int w = t >> 6, lane = t & 63;
  const int q = lane & 31, hi = lane >> 5;
  const int qg = w >> 1;   // q-group (0,1)
  const int kg = w & 1;    // k-group (0,1)

  const int flat = blockIdx.x;          // 0..2047
  const int xcd = flat & 7;
  const int j = flat >> 3;              // 0..255
  const int bh = xcd * 8 + (j & 7);
  const int qb = j >> 3;                // 0..31
  const int b = bh >> 4, h = bh & 15;
  const int q0 = qb * 64;
  const int qcol = h * 64, kcol = DD + h * 64;

  const int r0 = t >> 3;                       // 0..31
  const int sc = ((t & 7) ^ (r0 & 7)) * 8;
  const int ldst = (t & ~63) * 16;             // wave-uniform byte base
  const u16* Ksrc = qkv + (size_t)(b * SS + r0) * 3072 + kcol + sc;
  const u16* Vsrc = vt + (size_t)(bh * 64 + r0) * SS + sc;

  // ---- stage Q (64 rows x 64d = 8KB), extract B-frags ----
  {
    const u16* Qsrc = qkv + (size_t)(b * SS + q0 + r0) * 3072 + qcol + sc;
    gload16(Qsrc, (char*)lds + ldst);
    gload16(Qsrc + (size_t)32 * 3072, (char*)lds + 4096 + ldst);
  }
  WAITVM(0);
  RAWBAR();
  s16x8 qf[4];
  {
    const u16* Qw = lds + qg * 2048;  // q-group's 32 rows
#pragma unroll
    for (int s = 0; s < 4; ++s) qf[s] = ldfrag(Qw, q, 32 * s + 16 * hi);
  }
  asm volatile("s_waitcnt lgkmcnt(0)" ::: "memory");
  __builtin_amdgcn_sched_barrier(0);
  RAWBAR();

  gload16(Ksrc, (char*)lds + ldst);
  gload16(Ksrc + (size_t)32 * 3072, (char*)lds + 4096 + ldst);
  gload16(Vsrc, (char*)lds + 8192 + ldst);
  gload16(Vsrc + 32 * SS, (char*)lds + 12288 + ldst);
  WAITVM(0);
  RAWBAR();

  s16x8 onesv;
#pragma unroll
  for (int i = 0; i < 8; ++i) onesv[i] = (short)0x3F80;  // bf16 1.0

  f32x16 zf;
#pragma unroll
  for (int i = 0; i < 16; ++i) zf[i] = 0.f;

  f32x16 oac0, oac1, lacc;
#pragma unroll
  for (int i = 0; i < 16; ++i) { oac0[i] = 0.f; oac1[i] = 0.f; lacc[i] = 0.f; }

  for (int kt = 0; kt < SS / 64; ++kt) {
    const int cur = kt & 1;
    const u16* Kc = lds + cur * 8192;
    const u16* Vc = Kc + 4096;
    if (kt + 1 < SS / 64) {
      const size_t ko = (size_t)(kt + 1) * 64 * 3072;
      const int vo = (kt + 1) * 64;
      char* base = (char*)lds + (cur ^ 1) * 16384;
      gload16(Ksrc + ko, base + ldst);
      gload16(Ksrc + ko + (size_t)32 * 3072, base + 4096 + ldst);
      gload16(Vsrc + vo, base + 8192 + ldst);
      gload16(Vsrc + vo + 32 * SS, base + 12288 + ldst);
    }

    // ---- QK^T for this wave's 32 keys: S^T[32k][32q] ----
    __builtin_amdgcn_s_setprio(1);
    s16x8 k0 = ldfrag(Kc, kg * 32 + q, 16 * hi);
    f32x16 sa = MFMA32(k0, qf[0], zf);
#pragma unroll
    for (int s = 1; s < 4; ++s) {
      s16x8 ks = ldfrag(Kc, kg * 32 + q, 32 * s + 16 * hi);
      sa = MFMA32(ks, qf[s], sa);
    }
    __builtin_amdgcn_s_setprio(0);

    // ---- P = exp2(s) (Q pre-scaled; shift-free softmax numerator) ----
#pragma unroll
    for (int i = 0; i < 16; ++i) sa[i] = exp2f(sa[i]);

    // ---- pack P frags + PV (O^T = V^T P^T), l via ones-MFMA ----
    __builtin_amdgcn_s_setprio(1);
#pragma unroll
    for (int sp = 0; sp < 2; ++sp) {
      const int rb = 8 * sp;
      unsigned x0 = cvtpk_bf16(sa[rb + 0], sa[rb + 1]);
      unsigned x1 = cvtpk_bf16(sa[rb + 2], sa[rb + 3]);
      unsigned y0 = cvtpk_bf16(sa[rb + 4], sa[rb + 5]);
      unsigned y1 = cvtpk_bf16(sa[rb + 6], sa[rb + 7]);
      asm("v_permlane32_swap_b32 %0, %1" : "+v"(x0), "+v"(y0));
      asm("v_permlane32_swap_b32 %0, %1" : "+v"(x1), "+v"(y1));
      union { unsigned u[4]; s16x8 v; } pf;
      pf.u[0] = x0; pf.u[1] = x1; pf.u[2] = y0; pf.u[3] = y1;
      s16x8 v0 = ldfrag(Vc, q, kg * 64 + 32 * sp + 16 * hi);
      s16x8 v1 = ldfrag(Vc, 32 + q, kg * 64 + 32 * sp + 16 * hi);
      oac0 = MFMA32(v0, pf.v, oac0);
      oac1 = MFMA32(v1, pf.v, oac1);
      lacc = MFMA32(onesv, pf.v, lacc);
    }
    __builtin_amdgcn_s_setprio(0);

    WAITVM(0);
    RAWBAR();
  }

  // ---- combine k-group partials (pure sums) ----
  __syncthreads();
  float* red = (float*)lds;  // 2 q-groups x 64 lanes x 33 f32 = 16.9KB
  if (kg == 1) {
    float* myr = red + (qg * 64 + lane) * 33;
#pragma unroll
    for (int i = 0; i < 16; ++i) { myr[i] = oac0[i]; myr[16 + i] = oac1[i]; }
    myr[32] = lacc[0];
  }
  __syncthreads();
  if (kg == 0) {
    const float* pr = red + (qg * 64 + lane) * 33;
#pragma unroll
    for (int i = 0; i < 16; ++i) { oac0[i] += pr[i]; oac1[i] += pr[16 + i]; }
    const float inv = 1.f / (lacc[0] + pr[32]);
    const size_t row = (size_t)(b * SS + q0 + qg * 32 + q);
    u16* orow = xb + row * DD + qcol;
#pragma unroll
    for (int rr = 0; rr < 4; ++rr) {
      uint2 pw0, pw1;
      pw0.x = cvtpk_bf16(oac0[4 * rr] * inv, oac0[4 * rr + 1] * inv);
      pw0.y = cvtpk_bf16(oac0[4 * rr + 2] * inv, oac0[4 * rr + 3] * inv);
      pw1.x = cvtpk_bf16(oac1[4 * rr] * inv, oac1[4 * rr + 1] * inv);
      pw1.y = cvtpk_bf16(oac1[4 * rr + 2] * inv, oac1[4 * rr + 3] * inv);
      *(uint2*)(orow + 8 * rr + 4 * hi) = pw0;
      *(uint2*)(orow + 32 + 8 * rr + 4 * hi) = pw1;
    }
  }
}

// ---------------------------------------------------------------------------
// helpers
// ---------------------------------------------------------------------------
__global__ __launch_bounds__(256) void cvt_bf16(const float* __restrict__ x,
                                                u16* __restrict__ y, int n4) {
  int i = blockIdx.x * 256 + threadIdx.x;
  if (i < n4) {
    float4 v = ((const float4*)x)[i];
    u16x4 o;
    o[0] = f2bf(v.x); o[1] = f2bf(v.y); o[2] = f2bf(v.z); o[3] = f2bf(v.w);
    ((u16x4*)y)[i] = o;
  }
}

__global__ __launch_bounds__(256) void transpose_w(const float* __restrict__ W,
                                                   u16* __restrict__ Wt,
                                                   int K, int N) {
  __shared__ float T[32][33];
  const int n0 = blockIdx.x * 32, k0 = blockIdx.y * 32;
  const int t = threadIdx.x;
  const int r = t >> 3, c = (t & 7) * 4;
  float4 v = *(const float4*)&W[(size_t)(k0 + r) * N + n0 + c];
  T[r][c] = v.x; T[r][c + 1] = v.y; T[r][c + 2] = v.z; T[r][c + 3] = v.w;
  __syncthreads();
  const int a = t >> 3, b0 = (t & 7) * 4;
  u16x4 o;
#pragma unroll
  for (int j = 0; j < 4; ++j) o[j] = f2bf(T[b0 + j][a]);
  *(u16x4*)&Wt[(size_t)(n0 + a) * K + k0 + b0] = o;
}

__global__ __launch_bounds__(256) void vtrans(const u16* __restrict__ qkv,
                                              u16* __restrict__ vt) {
  __shared__ u16 T[64 * 72];
  const int t = threadIdx.x;
  const int bh = blockIdx.y, b = bh >> 4, h = bh & 15;
  const int s0 = blockIdx.x * 64;
  const int vcol = 2048 + h * 64;
#pragma unroll
  for (int i = 0; i < 2; ++i) {
    int c = i * 256 + t;
    int sr = c >> 3, dc = (c & 7) * 8;
    *(u16x8*)&T[sr * 72 + dc] =
        *(const u16x8*)&qkv[(size_t)(b * SS + s0 + sr) * 3072 + vcol + dc];
  }
  __syncthreads();
#pragma unroll
  for (int i = 0; i < 2; ++i) {
    int c = i * 256 + t;
    int d = c >> 3, scnk = (c & 7) * 8;
    u16x8 o;
#pragma unroll
    for (int jj = 0; jj < 8; ++jj) o[jj] = T[(scnk + jj) * 72 + d];
    *(u16x8*)&vt[(size_t)(bh * 64 + d) * SS + s0 + scnk] = o;
  }
}

__global__ __launch_bounds__(256) void concat3(const float* __restrict__ a,
                                               const float* __restrict__ b,
                                               const float* __restrict__ c,
                                               float* __restrict__ o) {
  int i = blockIdx.x * 256 + threadIdx.x;
  if (i < 3072)
    o[i] = i < 1024 ? a[i] : (i < 2048 ? b[i - 1024] : c[i - 2048]);
}

template <int WB>
__global__ __launch_bounds__(256) void ln_res(
    const float* __restrict__ X, const float* __restrict__ R,
    const float* __restrict__ g, const float* __restrict__ b,
    float* __restrict__ Y, u16* __restrict__ Yb) {
  const int row = blockIdx.x;
  const int t = threadIdx.x;
  const size_t off = (size_t)row * DD + t * 4;

  float4 x4 = *(const float4*)&X[off];
  float4 r4 = *(const float4*)&R[off];
  float v0 = x4.x + r4.x, v1 = x4.y + r4.y, v2 = x4.z + r4.z, v3 = x4.w + r4.w;

  float s1 = v0 + v1 + v2 + v3;
  float s2 = v0 * v0 + v1 * v1 + v2 * v2 + v3 * v3;
#pragma unroll
  for (int o = 1; o < 64; o <<= 1) {
    s1 += __shfl_xor(s1, o);
    s2 += __shfl_xor(s2, o);
  }
  __shared__ float red1[4], red2[4];
  if ((t & 63) == 0) {
    red1[t >> 6] = s1;
    red2[t >> 6] = s2;
  }
  __syncthreads();
  s1 = red1[0] + red1[1] + red1[2] + red1[3];
  s2 = red2[0] + red2[1] + red2[2] + red2[3];

  const float mu = s1 * (1.f / DD);
  const float var = s2 * (1.f / DD) - mu * mu;
  const float rs = rsqrtf(var + 1e-5f);

  float4 g4 = *(const float4*)&g[t * 4];
  float4 b4 = *(const float4*)&b[t * 4];
  float4 y;
  y.x = (v0 - mu) * rs * g4.x + b4.x;
  y.y = (v1 - mu) * rs * g4.y + b4.y;
  y.z = (v2 - mu) * rs * g4.z + b4.z;
  y.w = (v3 - mu) * rs * g4.w + b4.w;
  *(float4*)&Y[off] = y;
  if (WB) {
    u16x4 o;
    o[0] = f2bf(y.x); o[1] = f2bf(y.y); o[2] = f2bf(y.z); o[3] = f2bf(y.w);
    *(u16x4*)&Yb[off] = o;
  }
}

// ---------------------------------------------------------------------------
extern "C" void kernel_launch(void* const* d_in, const int* in_sizes, int n_in,
                              void* d_out, int out_size, void* d_ws,
                              size_t ws_size, hipStream_t stream) {
  const float* src = (const float*)d_in[0];
  const float* Wq  = (const float*)d_in[1];
  const float* bq  = (const float*)d_in[2];
  const float* Wk  = (const float*)d_in[3];
  const float* bk  = (const float*)d_in[4];
  const float* Wv  = (const float*)d_in[5];
  const float* bv  = (const float*)d_in[6];
  const float* Wo  = (const float*)d_in[7];
  const float* bo  = (const float*)d_in[8];
  const float* g1  = (const float*)d_in[9];
  const float* b1  = (const float*)d_in[10];
  const float* W1  = (const float*)d_in[11];
  const float* bf1 = (const float*)d_in[12];
  const float* W2  = (const float*)d_in[13];
  const float* bf2 = (const float*)d_in[14];
  const float* g2  = (const float*)d_in[15];
  const float* b2  = (const float*)d_in[16];

  char* W = (char*)d_ws;
  u16*   wqkvT = (u16*)  (W + 0);
  u16*   woT   = (u16*)  (W + 6291456);
  u16*   w1T   = (u16*)  (W + 8388608);
  u16*   w2T   = (u16*)  (W + 16777216);
  float* bqkv  = (float*)(W + 25165824);
  u16*   srcb  = (u16*)  (W + 25178112);
  u16*   qkv   = (u16*)  (W + 41955328);
  u16*   vt    = (u16*)  (W + 92286976);
  u16*   xb    = (u16*)  (W + 109064192);
  float* pb    = (float*)(W + 125841408);
  float* s1f   = (float*)(W + 159395840);
  u16*   s1bb  = (u16*)  (W + 109064192);
  u16*   f1b   = (u16*)  (W + 41955328);
  float* f2b   = (float*)(W + 125841408);

  dim3 blk(256);

  cvt_bf16<<<8192, blk, 0, stream>>>(src, srcb, MR * DD / 4);
  transpose_w<<<dim3(32, 32), blk, 0, stream>>>(Wq, wqkvT, DD, DD);
  transpose_w<<<dim3(32, 32), blk, 0, stream>>>(Wk, wqkvT + (size_t)1024 * 1024, DD, DD);
  transpose_w<<<dim3(32, 32), blk, 0, stream>>>(Wv, wqkvT + (size_t)2048 * 1024, DD, DD);
  transpose_w<<<dim3(32, 32), blk, 0, stream>>>(Wo, woT, DD, DD);
  transpose_w<<<dim3(128, 32), blk, 0, stream>>>(W1, w1T, DD, PFF);
  transpose_w<<<dim3(32, 128), blk, 0, stream>>>(W2, w2T, PFF, DD);
  concat3<<<12, blk, 0, stream>>>(bq, bk, bv, bqkv);

  gemm256<256, 0, 1, 1><<<384, 512, 0, stream>>>(srcb, wqkvT, bqkv, nullptr,
                                                 qkv, MR, 3072, DD, 12);
  vtrans<<<dim3(32, 64), blk, 0, stream>>>(qkv, vt);
  attn_mfma<<<2048, 256, 0, stream>>>(qkv, vt, xb);
  gemm256<128, 0, 0, 0><<<256, 512, 0, stream>>>(xb, woT, bo, pb, nullptr,
                                                 MR, DD, DD, 8);
  ln_res<1><<<MR, blk, 0, stream>>>(src, pb, g1, b1, s1f, s1bb);
  gemm256<256, 1, 1, 0><<<512, 512, 0, stream>>>(s1bb, w1T, bf1, nullptr, f1b,
                                                 MR, PFF, DD, 16);
  gemm256<128, 0, 0, 0><<<256, 512, 0, stream>>>(f1b, w2T, bf2, f2b, nullptr,
                                                 MR, DD, PFF, 8);
  ln_res<0><<<MR, blk, 0, stream>>>(s1f, f2b, g2, b2, (float*)d_out, nullptr);
}